// Round 12
// baseline (270.040 us; speedup 1.0000x reference)
//
#include <hip/hip_runtime.h>
#include <cstdint>
#include <cstddef>

// ---------------------------------------------------------------------------
// MLA forward (B=2, S=2048, DIM=2048, H=16, Q_RANK=KV_RANK=512,
//              D_NOPE=128, D_ROPE=64, D_V=128, D_QK=192)
// Round 12: flash reverted to R8-exact v6 (best measured: 83.5us — 4-wave,
//           QBLK=64, grid 1024, monotone longest-first). q-GEMM and kv-GEMM
//           merged into one 896-block dispatch (3.5 blocks/CU tail).
//           rmsnorm2 fusion kept. All other pieces = round-10 proven.
// ---------------------------------------------------------------------------

typedef unsigned short u16;
typedef unsigned int u32;
typedef unsigned long long u64;
typedef __attribute__((ext_vector_type(8))) short bf16x8;
typedef __attribute__((ext_vector_type(4))) float floatx4;

#define MFMA16x16x32 __builtin_amdgcn_mfma_f32_16x16x32_bf16

#define QSCALE 0.10411755f      // 192^-0.5 * log2(e)
#define THR_L2 11.541560f       // defer-max threshold 8.0 * log2(e)

__device__ __forceinline__ u16 f2bf(float f) {
  u32 u = __float_as_uint(f);
  u32 r = (u + 0x7fffu + ((u >> 16) & 1u)) >> 16;
  return (u16)r;
}
__device__ __forceinline__ float bf2f(u16 b) {
  return __uint_as_float(((u32)b) << 16);
}
__device__ __forceinline__ u32 cvtpk(float lo, float hi) {
  u32 r;
  asm("v_cvt_pk_bf16_f32 %0, %1, %2" : "=v"(r) : "v"(lo), "v"(hi));
  return r;
}
__device__ __forceinline__ void gload16(const void* g, void* l) {
  __builtin_amdgcn_global_load_lds(
      (const __attribute__((address_space(1))) void*)g,
      (__attribute__((address_space(3))) void*)l, 16, 0, 0);
}

// ---------------- fused f32 -> bf16 convert (6 segments, 1 dispatch) --------
__global__ __launch_bounds__(256) void cvt_all(
    const float* __restrict__ s0, const float* __restrict__ s1,
    const float* __restrict__ s2, const float* __restrict__ s3,
    const float* __restrict__ s4, const float* __restrict__ s5,
    u16* __restrict__ d0, u16* __restrict__ d1, u16* __restrict__ d2,
    u16* __restrict__ d3, u16* __restrict__ d4, u16* __restrict__ d5) {
  constexpr int ST1 = 2097152;            // x
  constexpr int ST2 = ST1 + 262144;       // wq_a
  constexpr int ST3 = ST2 + 294912;       // wkv_a
  constexpr int ST4 = ST3 + 393216;       // wq_b
  constexpr int ST5 = ST4 + 524288;       // wkv_b
  constexpr int TOT = ST5 + 1048576;      // wo
  int i = blockIdx.x * 256 + threadIdx.x;
  int stride = gridDim.x * 256;
  for (; i < TOT; i += stride) {
    const float* sp;
    u16* dp;
    int j;
    if (i < ST1)      { sp = s0; dp = d0; j = i; }
    else if (i < ST2) { sp = s1; dp = d1; j = i - ST1; }
    else if (i < ST3) { sp = s2; dp = d2; j = i - ST2; }
    else if (i < ST4) { sp = s3; dp = d3; j = i - ST3; }
    else if (i < ST5) { sp = s4; dp = d4; j = i - ST4; }
    else              { sp = s5; dp = d5; j = i - ST5; }
    float4 v = ((const float4*)sp)[j];
    ushort4 o;
    o.x = f2bf(v.x); o.y = f2bf(v.y); o.z = f2bf(v.z); o.w = f2bf(v.w);
    ((ushort4*)dp)[j] = o;
  }
}

// ---------------- gemm8: 512 thr, 8 waves (2M x 4N), BMxBN, BK=32 -----------
// 2-deep pipeline (proven): vmcnt(S) -> bar -> ds_read frags -> lgkmcnt(0) ->
// bar (read-release) -> STAGE(kt+2) -> MFMA cluster.
// EPI: 0 f32 C; 1 bf16 C.
template <int BM, int BN, int EPI>
__global__ __launch_bounds__(512) void gemm8(const u16* __restrict__ A,
                                             const u16* __restrict__ B,
                                             void* __restrict__ Cv,
                                             int M, int N, int K) {
  constexpr int WM = BM / 2;
  constexpr int AF = WM / 16;
  constexpr int WN = BN / 4;
  constexpr int FN = WN / 16;
  constexpr int LA = BM * 4 / 512;
  constexpr int LB = BN * 4 / 512;
  constexpr int S = LA + LB;
  __shared__ alignas(16) u16 As[2][BM * 32];
  __shared__ alignas(16) u16 Bs[2][BN * 32];
  const int m0 = blockIdx.y * BM, n0 = blockIdx.x * BN;
  const int t = threadIdx.x;
  const int wv = t >> 6, lane = t & 63, g = lane >> 4, qq = lane & 15;
  const int wr = wv >> 2, wc = wv & 3;
  const int fsw = (qq >> 1) & 3;
  size_t aoff[LA], boff[LB];
#pragma unroll
  for (int i = 0; i < LA; ++i) {
    int seg = t + i * 512;
    int row = seg >> 2, sl = seg & 3;
    aoff[i] = (size_t)(m0 + row) * K + (sl ^ ((row >> 1) & 3)) * 8;
  }
#pragma unroll
  for (int i = 0; i < LB; ++i) {
    int seg = t + i * 512;
    int row = seg >> 2, sl = seg & 3;
    boff[i] = (size_t)(n0 + row) * K + (sl ^ ((row >> 1) & 3)) * 8;
  }
  const floatx4 fz = {0.f, 0.f, 0.f, 0.f};
  floatx4 acc[AF][FN];
#pragma unroll
  for (int m = 0; m < AF; ++m)
#pragma unroll
    for (int n = 0; n < FN; ++n) acc[m][n] = fz;

#define GS8(buf, k0)                                                          \
  {                                                                           \
    _Pragma("unroll") for (int i = 0; i < LA; ++i)                            \
        gload16(&A[aoff[i] + (k0)], &As[buf][(size_t)(wv * 64 + i * 512) * 8]); \
    _Pragma("unroll") for (int i = 0; i < LB; ++i)                            \
        gload16(&B[boff[i] + (k0)], &Bs[buf][(size_t)(wv * 64 + i * 512) * 8]); \
  }

  const int nk = K >> 5;
  GS8(0, 0);
  GS8(1, 32);
  for (int kt = 0; kt < nk; ++kt) {
    asm volatile("" ::: "memory");
    if (kt + 1 < nk) {
      if constexpr (S == 4)
        asm volatile("s_waitcnt vmcnt(4)" ::: "memory");
      else if constexpr (S == 3)
        asm volatile("s_waitcnt vmcnt(3)" ::: "memory");
      else
        asm volatile("s_waitcnt vmcnt(2)" ::: "memory");
    } else {
      asm volatile("s_waitcnt vmcnt(0)" ::: "memory");
    }
    __builtin_amdgcn_s_barrier();
    asm volatile("" ::: "memory");
    const u16* Ab = &As[kt & 1][0];
    const u16* Bb = &Bs[kt & 1][0];
    bf16x8 af[AF], bfr[FN];
#pragma unroll
    for (int m = 0; m < AF; ++m)
      af[m] = *(const bf16x8*)&Ab[(wr * WM + m * 16 + qq) * 32 + ((g ^ fsw) * 8)];
#pragma unroll
    for (int n = 0; n < FN; ++n)
      bfr[n] = *(const bf16x8*)&Bb[(wc * WN + n * 16 + qq) * 32 + ((g ^ fsw) * 8)];
    asm volatile("s_waitcnt lgkmcnt(0)" ::: "memory");
    __builtin_amdgcn_s_barrier();
    asm volatile("" ::: "memory");
    if (kt + 2 < nk) GS8(kt & 1, (kt + 2) * 32);
    __builtin_amdgcn_s_setprio(1);
#pragma unroll
    for (int m = 0; m < AF; ++m)
#pragma unroll
      for (int n = 0; n < FN; ++n)
        acc[m][n] = MFMA16x16x32(af[m], bfr[n], acc[m][n], 0, 0, 0);
    __builtin_amdgcn_s_setprio(0);
  }
#undef GS8

#pragma unroll
  for (int m = 0; m < AF; ++m)
#pragma unroll
    for (int n = 0; n < FN; ++n)
#pragma unroll
      for (int r = 0; r < 4; ++r) {
        int row = m0 + wr * WM + m * 16 + 4 * g + r;
        int col = n0 + wc * WN + n * 16 + qq;
        if constexpr (EPI == 1)
          ((u16*)Cv)[(size_t)row * N + col] = f2bf(acc[m][n][r]);
        else
          ((float*)Cv)[(size_t)row * N + col] = acc[m][n][r];
      }
}

// ---------------- merged q+kv GEMM: 896 blocks, BM=128, BN=256, K=512 -------
// blockIdx.x < 12: q GEMM (A=qlatn, B=wqbb, N=3072) with rope/scale epilogue.
// else: kv GEMM (A=kvlatn, B=wkvbb, N=4096) with pack-k / transpose-v epi.
__global__ __launch_bounds__(512) void gemm_qkv(
    const u16* __restrict__ Aq, const u16* __restrict__ Bq,
    const u16* __restrict__ Akv, const u16* __restrict__ Bkv,
    u16* __restrict__ qbf, u16* __restrict__ kbf, u16* __restrict__ vt,
    const float* __restrict__ fcp) {
  constexpr int K = 512;
  __shared__ alignas(16) u16 As[2][128 * 32];
  __shared__ alignas(16) u16 Bs[2][256 * 32];
  const bool isq = blockIdx.x < 12;
  const u16* A = isq ? Aq : Akv;
  const u16* B = isq ? Bq : Bkv;
  const int m0 = blockIdx.y * 128;
  const int n0 = (isq ? blockIdx.x : blockIdx.x - 12) * 256;
  const int t = threadIdx.x;
  const int wv = t >> 6, lane = t & 63, g = lane >> 4, qq = lane & 15;
  const int wr = wv >> 2, wc = wv & 3;
  const int fsw = (qq >> 1) & 3;
  size_t aoff[1], boff[2];
  {
    int row = t >> 2, sl = t & 3;
    aoff[0] = (size_t)(m0 + row) * K + (sl ^ ((row >> 1) & 3)) * 8;
  }
#pragma unroll
  for (int i = 0; i < 2; ++i) {
    int seg = t + i * 512;
    int row = seg >> 2, sl = seg & 3;
    boff[i] = (size_t)(n0 + row) * K + (sl ^ ((row >> 1) & 3)) * 8;
  }
  const floatx4 fz = {0.f, 0.f, 0.f, 0.f};
  floatx4 acc[4][4];
#pragma unroll
  for (int m = 0; m < 4; ++m)
#pragma unroll
    for (int n = 0; n < 4; ++n) acc[m][n] = fz;

#define GSQ(buf, k0)                                                          \
  {                                                                           \
    gload16(&A[aoff[0] + (k0)], &As[buf][(size_t)(wv * 64) * 8]);             \
    _Pragma("unroll") for (int i = 0; i < 2; ++i)                             \
        gload16(&B[boff[i] + (k0)], &Bs[buf][(size_t)(wv * 64 + i * 512) * 8]); \
  }

  const int nk = K >> 5;  // 16
  GSQ(0, 0);
  GSQ(1, 32);
  for (int kt = 0; kt < nk; ++kt) {
    asm volatile("" ::: "memory");
    if (kt + 1 < nk)
      asm volatile("s_waitcnt vmcnt(3)" ::: "memory");
    else
      asm volatile("s_waitcnt vmcnt(0)" ::: "memory");
    __builtin_amdgcn_s_barrier();
    asm volatile("" ::: "memory");
    const u16* Ab = &As[kt & 1][0];
    const u16* Bb = &Bs[kt & 1][0];
    bf16x8 af[4], bfr[4];
#pragma unroll
    for (int m = 0; m < 4; ++m)
      af[m] = *(const bf16x8*)&Ab[(wr * 64 + m * 16 + qq) * 32 + ((g ^ fsw) * 8)];
#pragma unroll
    for (int n = 0; n < 4; ++n)
      bfr[n] = *(const bf16x8*)&Bb[(wc * 64 + n * 16 + qq) * 32 + ((g ^ fsw) * 8)];
    asm volatile("s_waitcnt lgkmcnt(0)" ::: "memory");
    __builtin_amdgcn_s_barrier();
    asm volatile("" ::: "memory");
    if (kt + 2 < nk) GSQ(kt & 1, (kt + 2) * 32);
    __builtin_amdgcn_s_setprio(1);
#pragma unroll
    for (int m = 0; m < 4; ++m)
#pragma unroll
      for (int n = 0; n < 4; ++n)
        acc[m][n] = MFMA16x16x32(af[m], bfr[n], acc[m][n], 0, 0, 0);
    __builtin_amdgcn_s_setprio(0);
  }
#undef GSQ

#pragma unroll
  for (int m = 0; m < 4; ++m)
#pragma unroll
    for (int n = 0; n < 4; ++n) {
      const int col16 = n0 + wc * 64 + n * 16;
      if (isq) {  // q: rope+scale pack -> qbf [bh][s][192]
        const int h = col16 / 192;
        const int jb = col16 - h * 192 + qq;
#pragma unroll
        for (int r = 0; r < 4; ++r) {
          int row = m0 + wr * 64 + m * 16 + 4 * g + r;
          int b = row >> 11, s = row & 2047;
          float own = acc[m][n][r];
          float par = __shfl_xor(own, 1);
          if ((qq & 1) == 0) {
            u32 w;
            if (jb < 128) {
              w = cvtpk(own * QSCALE, par * QSCALE);
            } else {
              int jp = (jb - 128) >> 1;
              float c = fcp[(s * 32 + jp) * 2];
              float sn = fcp[(s * 32 + jp) * 2 + 1];
              w = cvtpk((own * c - par * sn) * QSCALE,
                        (own * sn + par * c) * QSCALE);
            }
            *(u32*)(qbf + ((size_t)(b * 16 + h) * 2048 + s) * 192 + jb) = w;
          }
        }
      } else {  // kv: pack-k nope / transpose-v
        const int h = col16 >> 8;
        const int jb = (col16 & 255) + qq;
        if (jb < 128) {
#pragma unroll
          for (int r = 0; r < 4; ++r) {
            int row = m0 + wr * 64 + m * 16 + 4 * g + r;
            int b = row >> 11, s = row & 2047;
            float own = acc[m][n][r];
            float par = __shfl_xor(own, 1);
            if ((qq & 1) == 0)
              *(u32*)(kbf + ((size_t)(b * 16 + h) * 2048 + s) * 192 + jb) =
                  cvtpk(own, par);
          }
        } else {
          int row0 = m0 + wr * 64 + m * 16 + 4 * g;
          int b = row0 >> 11, s0v = row0 & 2047;
          int dv = jb - 128;
          u32 lo = cvtpk(acc[m][n][0], acc[m][n][1]);
          u32 hi = cvtpk(acc[m][n][2], acc[m][n][3]);
          u64 w = (u64)lo | ((u64)hi << 32);
          *(u64*)(vt + ((size_t)(b * 16 + h) * 128 + dv) * 2048 + s0v) = w;
        }
      }
    }
}

// ---------------- fused RMSNorms: bid<4096 q-side, else kv-side -------------
__global__ __launch_bounds__(256) void rmsnorm2(const u16* __restrict__ ap,
                                                const float* __restrict__ qw,
                                                const float* __restrict__ kw,
                                                u16* __restrict__ qout,
                                                u16* __restrict__ kout) {
  const int bid = blockIdx.x, t = threadIdx.x;
  const bool isq = bid < 4096;
  const int row = isq ? bid : bid - 4096;
  const u16* in = ap + (size_t)row * 1280 + (isq ? 0 : 512);
  const float* w = isq ? qw : kw;
  u16* out = (isq ? qout : kout) + (size_t)row * 512;
  __shared__ float wsum[4];
  u32 wv2 = *(const u32*)&in[2 * t];
  float vx = bf2f((u16)wv2), vy = bf2f((u16)(wv2 >> 16));
  float ss = vx * vx + vy * vy;
#pragma unroll
  for (int off = 1; off < 64; off <<= 1) ss += __shfl_xor(ss, off);
  if ((t & 63) == 0) wsum[t >> 6] = ss;
  __syncthreads();
  float tot = wsum[0] + wsum[1] + wsum[2] + wsum[3];
  float r = rsqrtf(tot * (1.f / 512.f) + 1e-6f);
  *(u32*)&out[2 * t] = cvtpk(vx * r * w[2 * t], vy * r * w[2 * t + 1]);
}

// ---------------- RoPE k_pe (aproj bf16 cols 1024..1087) -> kbf bcast -------
__global__ __launch_bounds__(256) void rope_kpe_bcast(const u16* __restrict__ ap,
                                                      const float* __restrict__ fc,
                                                      u16* __restrict__ kbf) {
  int idx = blockIdx.x * 256 + threadIdx.x;  // 4096*32
  int row = idx >> 5, j = idx & 31;
  int b = row >> 11, s = row & 2047;
  u32 wv2 = *(const u32*)&ap[(size_t)row * 1280 + 1024 + 2 * j];
  float xr = bf2f((u16)wv2), xi = bf2f((u16)(wv2 >> 16));
  float c = fc[(s * 32 + j) * 2], sn = fc[(s * 32 + j) * 2 + 1];
  u32 w = cvtpk(xr * c - xi * sn, xr * sn + xi * c);
#pragma unroll
  for (int h = 0; h < 16; ++h)
    *(u32*)&kbf[((size_t)(b * 16 + h) * 2048 + s) * 192 + 128 + 2 * j] = w;
}

// ---------------- flash attention v6 (R8-exact; best measured) --------------
__global__ __launch_bounds__(256, 4) void flash_attn(const u16* __restrict__ Q,
                                                     const u16* __restrict__ Kc,
                                                     const u16* __restrict__ VT,
                                                     u16* __restrict__ O) {
  __shared__ alignas(16) u16 Ks[2][32 * 192];
  __shared__ alignas(16) u16 Vs[2][128 * 32];
  const int bid = blockIdx.x;
  const int qt = 31 - (bid >> 5);  // longest blocks first
  const int bh = bid & 31;
  const int t = threadIdx.x, wv = t >> 6, lane = t & 63;
  const int g = lane >> 4, qq = lane & 15;
  const int qrow0 = qt * 64 + wv * 16;
  const int my_last = qrow0 + 15;
  const int q_glob = qrow0 + qq;
  const int nkt = 2 * qt + 2;

  int koffg[3], voffg[2];
#pragma unroll
  for (int i = 0; i < 3; ++i) {
    int seg = t + i * 256;
    int row = seg / 24, sl = seg - row * 24;
    koffg[i] = row * 192 + (sl ^ ((row >> 1) & 7)) * 8;
  }
#pragma unroll
  for (int i = 0; i < 2; ++i) {
    int seg = t + i * 256;
    int row = seg >> 2, sl = seg & 3;
    voffg[i] = row * 2048 + (sl ^ ((row >> 1) & 3)) * 8;
  }
  const u16* Kt0 = Kc + (size_t)bh * 2048 * 192;
  const u16* Vt0 = VT + (size_t)bh * 128 * 2048;

  bf16x8 qf[6];
  {
    const u16* qp = Q + ((size_t)bh * 2048 + qrow0 + qq) * 192;
#pragma unroll
    for (int kk = 0; kk < 6; ++kk) qf[kk] = *(const bf16x8*)&qp[kk * 32 + g * 8];
  }
  asm volatile("s_waitcnt vmcnt(0)" ::: "memory");

  const floatx4 fz = {0.f, 0.f, 0.f, 0.f};
  floatx4 oacc[8];
  floatx4 oacc_l = fz;
#pragma unroll
  for (int d = 0; d < 8; ++d) oacc[d] = fz;
  float m_run = -1e30f;

  bf16x8 ones;
#pragma unroll
  for (int i = 0; i < 8; ++i) ones[i] = (short)0x3f80;

  const int krow0 = 2 * qq;
  const int krow1 = 2 * qq + 1;
  const int xrk = qq & 7;
  const int vsw = (qq >> 1) & 3;

#define STAGE(buf, kt)                                                       \
  {                                                                          \
    const u16* Kg = Kt0 + (size_t)(kt) * (32 * 192);                         \
    const u16* Vg = Vt0 + (kt) * 32;                                         \
    _Pragma("unroll") for (int i = 0; i < 3; ++i)                            \
        gload16(Kg + koffg[i], &Ks[buf][(size_t)(wv * 64 + i * 256) * 8]);   \
    _Pragma("unroll") for (int i = 0; i < 2; ++i)                            \
        gload16(Vg + voffg[i], &Vs[buf][(size_t)(wv * 64 + i * 256) * 8]);   \
  }

  STAGE(0, 0);
  for (int kt = 0; kt < nkt; ++kt) {
    const int k0 = kt * 32;
    asm volatile("" ::: "memory");
    if (kt + 1 < nkt) {
      STAGE((kt + 1) & 1, kt + 1);
      asm volatile("s_waitcnt vmcnt(5)" ::: "memory");
    } else {
      asm volatile("s_waitcnt vmcnt(0)" ::: "memory");
    }
    __builtin_amdgcn_s_barrier();
    asm volatile("" ::: "memory");
    if (k0 <= my_last) {
      const u16* Kb = &Ks[kt & 1][0];
      const u16* Vb = &Vs[kt & 1][0];
      floatx4 s0 = fz, s1 = fz;
      __builtin_amdgcn_s_setprio(1);
#pragma unroll
      for (int kk = 0; kk < 6; ++kk) {
        int sl = kk * 4 + g;
        bf16x8 a0 = *(const bf16x8*)&Kb[krow0 * 192 + ((sl ^ xrk) * 8)];
        bf16x8 a1 = *(const bf16x8*)&Kb[krow1 * 192 + ((sl ^ xrk) * 8)];
        s0 = MFMA16x16x32(a0, qf[kk], s0, 0, 0, 0);
        s1 = MFMA16x16x32(a1, qf[kk], s1, 0, 0, 0);
      }
      __builtin_amdgcn_s_setprio(0);
      float v[8];
      if (k0 + 31 <= qrow0) {
#pragma unroll
        for (int r = 0; r < 4; ++r) {
          v[r] = s0[r];
          v[4 + r] = s1[r];
        }
      } else {
#pragma unroll
        for (int r = 0; r < 4; ++r) {
          int key0 = k0 + 8 * g + 2 * r;
          v[r] = (key0 <= q_glob) ? s0[r] : -1e30f;
          v[4 + r] = (key0 + 1 <= q_glob) ? s1[r] : -1e30f;
        }
      }
      float mloc = fmaxf(fmaxf(fmaxf(v[0], v[1]), fmaxf(v[2], v[3])),
                         fmaxf(fmaxf(v[4], v[5]), fmaxf(v[6], v[7])));
      if (!__all(mloc <= m_run + THR_L2)) {
        float mx = fmaxf(mloc, __shfl_xor(mloc, 16));
        mx = fmaxf(mx, __shfl_xor(mx, 32));
        float m_new = fmaxf(m_run, mx);
        float alpha = exp2f(m_run - m_new);
        m_run = m_new;
#pragma unroll
        for (int d = 0; d < 8; ++d)
#pragma unroll
          for (int r = 0; r < 4; ++r) oacc[d][r] *= alpha;
#pragma unroll
        for (int r = 0; r < 4; ++r) oacc_l[r] *= alpha;
      }
      float pex[8];
#pragma unroll
      for (int i = 0; i < 8; ++i) pex[i] = exp2f(v[i] - m_run);
      bf16x8 pf;
      ((u32*)&pf)[0] = cvtpk(pex[0], pex[4]);
      ((u32*)&pf)[1] = cvtpk(pex[1], pex[5]);
      ((u32*)&pf)[2] = cvtpk(pex[2], pex[6]);
      ((u32*)&pf)[3] = cvtpk(pex[3], pex[7]);
      __builtin_amdgcn_s_setprio(1);
#pragma unroll
      for (int d = 0; d < 8; ++d) {
        bf16x8 vf = *(const bf16x8*)&Vb[(d * 16 + qq) * 32 + ((g ^ vsw) * 8)];
        oacc[d] = MFMA16x16x32(vf, pf, oacc[d], 0, 0, 0);
      }
      oacc_l = MFMA16x16x32(ones, pf, oacc_l, 0, 0, 0);
      __builtin_amdgcn_s_setprio(0);
    }
    asm volatile("" ::: "memory");
    __builtin_amdgcn_s_barrier();
  }
#undef STAGE
  float linv = 1.f / oacc_l[0];
  const int b = bh >> 4, h = bh & 15;
  size_t rowoff = ((size_t)b * 2048 + qrow0 + qq) * 2048 + h * 128 + 4 * g;
#pragma unroll
  for (int d = 0; d < 8; ++d) {
    u32 lo = cvtpk(oacc[d][0] * linv, oacc[d][1] * linv);
    u32 hi = cvtpk(oacc[d][2] * linv, oacc[d][3] * linv);
    u64 w = (u64)lo | ((u64)hi << 32);
    *(u64*)&O[rowoff + d * 16] = w;
  }
}

// ---------------------------------------------------------------------------
extern "C" void kernel_launch(void* const* d_in, const int* in_sizes, int n_in,
                              void* d_out, int out_size, void* d_ws,
                              size_t ws_size, hipStream_t stream) {
  (void)in_sizes; (void)n_in; (void)out_size;
  const float* x = (const float*)d_in[0];
  const float* fc = (const float*)d_in[1];
  const float* wqa = (const float*)d_in[2];
  const float* wqb = (const float*)d_in[3];
  const float* qnw = (const float*)d_in[4];
  const float* wkva = (const float*)d_in[5];
  const float* kvnw = (const float*)d_in[6];
  const float* wkvb = (const float*)d_in[7];
  const float* wo = (const float*)d_in[8];
  float* out = (float*)d_out;
  char* ws = (char*)d_ws;

  size_t off = 0;
  auto alloc = [&](size_t bytes) {
    size_t o = off;
    off += (bytes + 255) & ~(size_t)255;
    return o;
  };
  const size_t o_xbf = alloc(16777216);   // x bf16; later aliased by attn_out
  const size_t o_wa = alloc(5242880);     // merged [wq_a;wkv_a;pad] bf16 1280x2048
  const size_t o_wqb = alloc(3145728);
  const size_t o_wkvb = alloc(4194304);
  const size_t o_wo = alloc(8388608);
  const size_t o_qln = alloc(4194304);
  const size_t o_kvln = alloc(4194304);
  const size_t o_ap = alloc(10485760);    // aproj bf16 4096x1280
  const size_t o_qbf = alloc(25165824);   // q packed [bh][s][192] (pre-scaled)
  const size_t o_kbf = alloc(25165824);   // k packed [bh][s][192]
  const size_t o_vt = alloc(16777216);    // v^T [bh][128][2048]
  if (ws_size < off) return;

  u16* xbf = (u16*)(ws + o_xbf);
  u16* wab = (u16*)(ws + o_wa);
  u16* wqbb = (u16*)(ws + o_wqb);
  u16* wkvbb = (u16*)(ws + o_wkvb);
  u16* wob = (u16*)(ws + o_wo);
  u16* qlatn = (u16*)(ws + o_qln);
  u16* kvlatn = (u16*)(ws + o_kvln);
  u16* ap = (u16*)(ws + o_ap);
  u16* qbf = (u16*)(ws + o_qbf);
  u16* kbf = (u16*)(ws + o_kbf);
  u16* vt = (u16*)(ws + o_vt);
  u16* attnbf = (u16*)(ws + o_xbf);

  cvt_all<<<2048, 256, 0, stream>>>(x, wqa, wkva, wqb, wkvb, wo,
                                    xbf, wab, wab + 1048576, wqbb, wkvbb, wob);

  // merged down-projection (N padded 1088->1280), bf16 out; 320 blocks
  gemm8<128, 128, 1><<<dim3(10, 32), 512, 0, stream>>>(
      xbf, wab, ap, 4096, 1280, 2048);
  rmsnorm2<<<8192, 256, 0, stream>>>(ap, qnw, kvnw, qlatn, kvlatn);
  rope_kpe_bcast<<<512, 256, 0, stream>>>(ap, fc, kbf);

  // merged q+kv GEMM with fused epilogues; 896 blocks (3.5/CU)
  gemm_qkv<<<dim3(28, 32), 512, 0, stream>>>(qlatn, wqbb, kvlatn, wkvbb,
                                             qbf, kbf, vt, fc);

  // attention (1024 blocks x 256 thr) + output projection
  flash_attn<<<1024, 256, 0, stream>>>(qbf, kbf, vt, attnbf);
  gemm8<128, 128, 0><<<dim3(16, 32), 512, 0, stream>>>(
      attnbf, wob, out, 4096, 2048, 2048);
}

// Round 13
// 245.215 us; speedup vs baseline: 1.1012x; 1.1012x over previous
//
#include <hip/hip_runtime.h>
#include <cstdint>
#include <cstddef>

// ---------------------------------------------------------------------------
// MLA forward (B=2, S=2048, DIM=2048, H=16, Q_RANK=KV_RANK=512,
//              D_NOPE=128, D_ROPE=64, D_V=128, D_QK=192)
// Round 13: best-measured assembly. GEMM pipeline = round-10 exact (separate
//           gemm8 dispatches, 2-phase schedule, fused epilogues). Flash =
//           round-8 exact (monotone longest-first, 4-wave QBLK=64, 83.5us).
//           rmsnorm2 fusion kept.
// ---------------------------------------------------------------------------

typedef unsigned short u16;
typedef unsigned int u32;
typedef unsigned long long u64;
typedef __attribute__((ext_vector_type(8))) short bf16x8;
typedef __attribute__((ext_vector_type(4))) float floatx4;

#define MFMA16x16x32 __builtin_amdgcn_mfma_f32_16x16x32_bf16

#define QSCALE 0.10411755f      // 192^-0.5 * log2(e)
#define THR_L2 11.541560f       // defer-max threshold 8.0 * log2(e)

__device__ __forceinline__ u16 f2bf(float f) {
  u32 u = __float_as_uint(f);
  u32 r = (u + 0x7fffu + ((u >> 16) & 1u)) >> 16;
  return (u16)r;
}
__device__ __forceinline__ float bf2f(u16 b) {
  return __uint_as_float(((u32)b) << 16);
}
__device__ __forceinline__ u32 cvtpk(float lo, float hi) {
  u32 r;
  asm("v_cvt_pk_bf16_f32 %0, %1, %2" : "=v"(r) : "v"(lo), "v"(hi));
  return r;
}
__device__ __forceinline__ void gload16(const void* g, void* l) {
  __builtin_amdgcn_global_load_lds(
      (const __attribute__((address_space(1))) void*)g,
      (__attribute__((address_space(3))) void*)l, 16, 0, 0);
}

// ---------------- fused f32 -> bf16 convert (6 segments, 1 dispatch) --------
__global__ __launch_bounds__(256) void cvt_all(
    const float* __restrict__ s0, const float* __restrict__ s1,
    const float* __restrict__ s2, const float* __restrict__ s3,
    const float* __restrict__ s4, const float* __restrict__ s5,
    u16* __restrict__ d0, u16* __restrict__ d1, u16* __restrict__ d2,
    u16* __restrict__ d3, u16* __restrict__ d4, u16* __restrict__ d5) {
  constexpr int ST1 = 2097152;            // x
  constexpr int ST2 = ST1 + 262144;       // wq_a
  constexpr int ST3 = ST2 + 294912;       // wkv_a
  constexpr int ST4 = ST3 + 393216;       // wq_b
  constexpr int ST5 = ST4 + 524288;       // wkv_b
  constexpr int TOT = ST5 + 1048576;      // wo
  int i = blockIdx.x * 256 + threadIdx.x;
  int stride = gridDim.x * 256;
  for (; i < TOT; i += stride) {
    const float* sp;
    u16* dp;
    int j;
    if (i < ST1)      { sp = s0; dp = d0; j = i; }
    else if (i < ST2) { sp = s1; dp = d1; j = i - ST1; }
    else if (i < ST3) { sp = s2; dp = d2; j = i - ST2; }
    else if (i < ST4) { sp = s3; dp = d3; j = i - ST3; }
    else if (i < ST5) { sp = s4; dp = d4; j = i - ST4; }
    else              { sp = s5; dp = d5; j = i - ST5; }
    float4 v = ((const float4*)sp)[j];
    ushort4 o;
    o.x = f2bf(v.x); o.y = f2bf(v.y); o.z = f2bf(v.z); o.w = f2bf(v.w);
    ((ushort4*)dp)[j] = o;
  }
}

// ---------------- gemm8: 512 thr, 8 waves (2M x 4N), BMxBN, BK=32 -----------
// 2-deep pipeline (proven): vmcnt(S) -> bar -> ds_read frags -> lgkmcnt(0) ->
// bar (read-release) -> STAGE(kt+2) -> MFMA cluster.
// EPI: 0 f32 C; 1 bf16 C; 2 q rope+scale pack -> qbf; 3 kv pack -> kbf + vt.
template <int BM, int BN, int EPI>
__global__ __launch_bounds__(512) void gemm8(const u16* __restrict__ A,
                                             const u16* __restrict__ B,
                                             void* __restrict__ Cv,
                                             int M, int N, int K,
                                             const float* __restrict__ fcp,
                                             void* __restrict__ aux) {
  constexpr int WM = BM / 2;
  constexpr int AF = WM / 16;
  constexpr int WN = BN / 4;
  constexpr int FN = WN / 16;
  constexpr int LA = BM * 4 / 512;
  constexpr int LB = BN * 4 / 512;
  constexpr int S = LA + LB;
  __shared__ alignas(16) u16 As[2][BM * 32];
  __shared__ alignas(16) u16 Bs[2][BN * 32];
  const int m0 = blockIdx.y * BM, n0 = blockIdx.x * BN;
  const int t = threadIdx.x;
  const int wv = t >> 6, lane = t & 63, g = lane >> 4, qq = lane & 15;
  const int wr = wv >> 2, wc = wv & 3;
  const int fsw = (qq >> 1) & 3;
  size_t aoff[LA], boff[LB];
#pragma unroll
  for (int i = 0; i < LA; ++i) {
    int seg = t + i * 512;
    int row = seg >> 2, sl = seg & 3;
    aoff[i] = (size_t)(m0 + row) * K + (sl ^ ((row >> 1) & 3)) * 8;
  }
#pragma unroll
  for (int i = 0; i < LB; ++i) {
    int seg = t + i * 512;
    int row = seg >> 2, sl = seg & 3;
    boff[i] = (size_t)(n0 + row) * K + (sl ^ ((row >> 1) & 3)) * 8;
  }
  const floatx4 fz = {0.f, 0.f, 0.f, 0.f};
  floatx4 acc[AF][FN];
#pragma unroll
  for (int m = 0; m < AF; ++m)
#pragma unroll
    for (int n = 0; n < FN; ++n) acc[m][n] = fz;

#define GS8(buf, k0)                                                          \
  {                                                                           \
    _Pragma("unroll") for (int i = 0; i < LA; ++i)                            \
        gload16(&A[aoff[i] + (k0)], &As[buf][(size_t)(wv * 64 + i * 512) * 8]); \
    _Pragma("unroll") for (int i = 0; i < LB; ++i)                            \
        gload16(&B[boff[i] + (k0)], &Bs[buf][(size_t)(wv * 64 + i * 512) * 8]); \
  }

  const int nk = K >> 5;
  GS8(0, 0);
  GS8(1, 32);
  for (int kt = 0; kt < nk; ++kt) {
    asm volatile("" ::: "memory");
    if (kt + 1 < nk) {
      if constexpr (S == 4)
        asm volatile("s_waitcnt vmcnt(4)" ::: "memory");
      else if constexpr (S == 3)
        asm volatile("s_waitcnt vmcnt(3)" ::: "memory");
      else
        asm volatile("s_waitcnt vmcnt(2)" ::: "memory");
    } else {
      asm volatile("s_waitcnt vmcnt(0)" ::: "memory");
    }
    __builtin_amdgcn_s_barrier();
    asm volatile("" ::: "memory");
    const u16* Ab = &As[kt & 1][0];
    const u16* Bb = &Bs[kt & 1][0];
    bf16x8 af[AF], bfr[FN];
#pragma unroll
    for (int m = 0; m < AF; ++m)
      af[m] = *(const bf16x8*)&Ab[(wr * WM + m * 16 + qq) * 32 + ((g ^ fsw) * 8)];
#pragma unroll
    for (int n = 0; n < FN; ++n)
      bfr[n] = *(const bf16x8*)&Bb[(wc * WN + n * 16 + qq) * 32 + ((g ^ fsw) * 8)];
    asm volatile("s_waitcnt lgkmcnt(0)" ::: "memory");
    __builtin_amdgcn_s_barrier();
    asm volatile("" ::: "memory");
    if (kt + 2 < nk) GS8(kt & 1, (kt + 2) * 32);
    __builtin_amdgcn_s_setprio(1);
#pragma unroll
    for (int m = 0; m < AF; ++m)
#pragma unroll
      for (int n = 0; n < FN; ++n)
        acc[m][n] = MFMA16x16x32(af[m], bfr[n], acc[m][n], 0, 0, 0);
    __builtin_amdgcn_s_setprio(0);
  }
#undef GS8

#pragma unroll
  for (int m = 0; m < AF; ++m)
#pragma unroll
    for (int n = 0; n < FN; ++n) {
      const int col16 = n0 + wc * WN + n * 16;
      if constexpr (EPI == 0 || EPI == 1) {
#pragma unroll
        for (int r = 0; r < 4; ++r) {
          int row = m0 + wr * WM + m * 16 + 4 * g + r;
          int col = col16 + qq;
          if constexpr (EPI == 1)
            ((u16*)Cv)[(size_t)row * N + col] = f2bf(acc[m][n][r]);
          else
            ((float*)Cv)[(size_t)row * N + col] = acc[m][n][r];
        }
      } else if constexpr (EPI == 2) {
        const int h = col16 / 192;
        const int jb = col16 - h * 192 + qq;
#pragma unroll
        for (int r = 0; r < 4; ++r) {
          int row = m0 + wr * WM + m * 16 + 4 * g + r;
          int b = row >> 11, s = row & 2047;
          float own = acc[m][n][r];
          float par = __shfl_xor(own, 1);
          if ((qq & 1) == 0) {
            u32 w;
            if (jb < 128) {
              w = cvtpk(own * QSCALE, par * QSCALE);
            } else {
              int jp = (jb - 128) >> 1;
              float c = fcp[(s * 32 + jp) * 2];
              float sn = fcp[(s * 32 + jp) * 2 + 1];
              w = cvtpk((own * c - par * sn) * QSCALE,
                        (own * sn + par * c) * QSCALE);
            }
            *(u32*)((u16*)Cv + ((size_t)(b * 16 + h) * 2048 + s) * 192 + jb) = w;
          }
        }
      } else {  // EPI == 3
        const int h = col16 >> 8;
        const int jb = (col16 & 255) + qq;
        if (jb < 128) {
#pragma unroll
          for (int r = 0; r < 4; ++r) {
            int row = m0 + wr * WM + m * 16 + 4 * g + r;
            int b = row >> 11, s = row & 2047;
            float own = acc[m][n][r];
            float par = __shfl_xor(own, 1);
            if ((qq & 1) == 0)
              *(u32*)((u16*)Cv + ((size_t)(b * 16 + h) * 2048 + s) * 192 + jb) =
                  cvtpk(own, par);
          }
        } else {
          int row0 = m0 + wr * WM + m * 16 + 4 * g;
          int b = row0 >> 11, s0v = row0 & 2047;
          int dv = jb - 128;
          u32 lo = cvtpk(acc[m][n][0], acc[m][n][1]);
          u32 hi = cvtpk(acc[m][n][2], acc[m][n][3]);
          u64 w = (u64)lo | ((u64)hi << 32);
          *(u64*)((u16*)aux + ((size_t)(b * 16 + h) * 128 + dv) * 2048 + s0v) = w;
        }
      }
    }
}

// ---------------- fused RMSNorms: bid<4096 q-side, else kv-side -------------
__global__ __launch_bounds__(256) void rmsnorm2(const u16* __restrict__ ap,
                                                const float* __restrict__ qw,
                                                const float* __restrict__ kw,
                                                u16* __restrict__ qout,
                                                u16* __restrict__ kout) {
  const int bid = blockIdx.x, t = threadIdx.x;
  const bool isq = bid < 4096;
  const int row = isq ? bid : bid - 4096;
  const u16* in = ap + (size_t)row * 1280 + (isq ? 0 : 512);
  const float* w = isq ? qw : kw;
  u16* out = (isq ? qout : kout) + (size_t)row * 512;
  __shared__ float wsum[4];
  u32 wv2 = *(const u32*)&in[2 * t];
  float vx = bf2f((u16)wv2), vy = bf2f((u16)(wv2 >> 16));
  float ss = vx * vx + vy * vy;
#pragma unroll
  for (int off = 1; off < 64; off <<= 1) ss += __shfl_xor(ss, off);
  if ((t & 63) == 0) wsum[t >> 6] = ss;
  __syncthreads();
  float tot = wsum[0] + wsum[1] + wsum[2] + wsum[3];
  float r = rsqrtf(tot * (1.f / 512.f) + 1e-6f);
  *(u32*)&out[2 * t] = cvtpk(vx * r * w[2 * t], vy * r * w[2 * t + 1]);
}

// ---------------- RoPE k_pe (aproj bf16 cols 1024..1087) -> kbf bcast -------
__global__ __launch_bounds__(256) void rope_kpe_bcast(const u16* __restrict__ ap,
                                                      const float* __restrict__ fc,
                                                      u16* __restrict__ kbf) {
  int idx = blockIdx.x * 256 + threadIdx.x;  // 4096*32
  int row = idx >> 5, j = idx & 31;
  int b = row >> 11, s = row & 2047;
  u32 wv2 = *(const u32*)&ap[(size_t)row * 1280 + 1024 + 2 * j];
  float xr = bf2f((u16)wv2), xi = bf2f((u16)(wv2 >> 16));
  float c = fc[(s * 32 + j) * 2], sn = fc[(s * 32 + j) * 2 + 1];
  u32 w = cvtpk(xr * c - xi * sn, xr * sn + xi * c);
#pragma unroll
  for (int h = 0; h < 16; ++h)
    *(u32*)&kbf[((size_t)(b * 16 + h) * 2048 + s) * 192 + 128 + 2 * j] = w;
}

// ---------------- flash attention v6 (R8-exact; best measured 83.5us) -------
__global__ __launch_bounds__(256, 4) void flash_attn(const u16* __restrict__ Q,
                                                     const u16* __restrict__ Kc,
                                                     const u16* __restrict__ VT,
                                                     u16* __restrict__ O) {
  __shared__ alignas(16) u16 Ks[2][32 * 192];
  __shared__ alignas(16) u16 Vs[2][128 * 32];
  const int bid = blockIdx.x;
  const int qt = 31 - (bid >> 5);  // longest blocks first
  const int bh = bid & 31;
  const int t = threadIdx.x, wv = t >> 6, lane = t & 63;
  const int g = lane >> 4, qq = lane & 15;
  const int qrow0 = qt * 64 + wv * 16;
  const int my_last = qrow0 + 15;
  const int q_glob = qrow0 + qq;
  const int nkt = 2 * qt + 2;

  int koffg[3], voffg[2];
#pragma unroll
  for (int i = 0; i < 3; ++i) {
    int seg = t + i * 256;
    int row = seg / 24, sl = seg - row * 24;
    koffg[i] = row * 192 + (sl ^ ((row >> 1) & 7)) * 8;
  }
#pragma unroll
  for (int i = 0; i < 2; ++i) {
    int seg = t + i * 256;
    int row = seg >> 2, sl = seg & 3;
    voffg[i] = row * 2048 + (sl ^ ((row >> 1) & 3)) * 8;
  }
  const u16* Kt0 = Kc + (size_t)bh * 2048 * 192;
  const u16* Vt0 = VT + (size_t)bh * 128 * 2048;

  bf16x8 qf[6];
  {
    const u16* qp = Q + ((size_t)bh * 2048 + qrow0 + qq) * 192;
#pragma unroll
    for (int kk = 0; kk < 6; ++kk) qf[kk] = *(const bf16x8*)&qp[kk * 32 + g * 8];
  }
  asm volatile("s_waitcnt vmcnt(0)" ::: "memory");

  const floatx4 fz = {0.f, 0.f, 0.f, 0.f};
  floatx4 oacc[8];
  floatx4 oacc_l = fz;
#pragma unroll
  for (int d = 0; d < 8; ++d) oacc[d] = fz;
  float m_run = -1e30f;

  bf16x8 ones;
#pragma unroll
  for (int i = 0; i < 8; ++i) ones[i] = (short)0x3f80;

  const int krow0 = 2 * qq;
  const int krow1 = 2 * qq + 1;
  const int xrk = qq & 7;
  const int vsw = (qq >> 1) & 3;

#define STAGE(buf, kt)                                                       \
  {                                                                          \
    const u16* Kg = Kt0 + (size_t)(kt) * (32 * 192);                         \
    const u16* Vg = Vt0 + (kt) * 32;                                         \
    _Pragma("unroll") for (int i = 0; i < 3; ++i)                            \
        gload16(Kg + koffg[i], &Ks[buf][(size_t)(wv * 64 + i * 256) * 8]);   \
    _Pragma("unroll") for (int i = 0; i < 2; ++i)                            \
        gload16(Vg + voffg[i], &Vs[buf][(size_t)(wv * 64 + i * 256) * 8]);   \
  }

  STAGE(0, 0);
  for (int kt = 0; kt < nkt; ++kt) {
    const int k0 = kt * 32;
    asm volatile("" ::: "memory");
    if (kt + 1 < nkt) {
      STAGE((kt + 1) & 1, kt + 1);
      asm volatile("s_waitcnt vmcnt(5)" ::: "memory");
    } else {
      asm volatile("s_waitcnt vmcnt(0)" ::: "memory");
    }
    __builtin_amdgcn_s_barrier();
    asm volatile("" ::: "memory");
    if (k0 <= my_last) {
      const u16* Kb = &Ks[kt & 1][0];
      const u16* Vb = &Vs[kt & 1][0];
      floatx4 s0 = fz, s1 = fz;
      __builtin_amdgcn_s_setprio(1);
#pragma unroll
      for (int kk = 0; kk < 6; ++kk) {
        int sl = kk * 4 + g;
        bf16x8 a0 = *(const bf16x8*)&Kb[krow0 * 192 + ((sl ^ xrk) * 8)];
        bf16x8 a1 = *(const bf16x8*)&Kb[krow1 * 192 + ((sl ^ xrk) * 8)];
        s0 = MFMA16x16x32(a0, qf[kk], s0, 0, 0, 0);
        s1 = MFMA16x16x32(a1, qf[kk], s1, 0, 0, 0);
      }
      __builtin_amdgcn_s_setprio(0);
      float v[8];
      if (k0 + 31 <= qrow0) {
#pragma unroll
        for (int r = 0; r < 4; ++r) {
          v[r] = s0[r];
          v[4 + r] = s1[r];
        }
      } else {
#pragma unroll
        for (int r = 0; r < 4; ++r) {
          int key0 = k0 + 8 * g + 2 * r;
          v[r] = (key0 <= q_glob) ? s0[r] : -1e30f;
          v[4 + r] = (key0 + 1 <= q_glob) ? s1[r] : -1e30f;
        }
      }
      float mloc = fmaxf(fmaxf(fmaxf(v[0], v[1]), fmaxf(v[2], v[3])),
                         fmaxf(fmaxf(v[4], v[5]), fmaxf(v[6], v[7])));
      if (!__all(mloc <= m_run + THR_L2)) {
        float mx = fmaxf(mloc, __shfl_xor(mloc, 16));
        mx = fmaxf(mx, __shfl_xor(mx, 32));
        float m_new = fmaxf(m_run, mx);
        float alpha = exp2f(m_run - m_new);
        m_run = m_new;
#pragma unroll
        for (int d = 0; d < 8; ++d)
#pragma unroll
          for (int r = 0; r < 4; ++r) oacc[d][r] *= alpha;
#pragma unroll
        for (int r = 0; r < 4; ++r) oacc_l[r] *= alpha;
      }
      float pex[8];
#pragma unroll
      for (int i = 0; i < 8; ++i) pex[i] = exp2f(v[i] - m_run);
      bf16x8 pf;
      ((u32*)&pf)[0] = cvtpk(pex[0], pex[4]);
      ((u32*)&pf)[1] = cvtpk(pex[1], pex[5]);
      ((u32*)&pf)[2] = cvtpk(pex[2], pex[6]);
      ((u32*)&pf)[3] = cvtpk(pex[3], pex[7]);
      __builtin_amdgcn_s_setprio(1);
#pragma unroll
      for (int d = 0; d < 8; ++d) {
        bf16x8 vf = *(const bf16x8*)&Vb[(d * 16 + qq) * 32 + ((g ^ vsw) * 8)];
        oacc[d] = MFMA16x16x32(vf, pf, oacc[d], 0, 0, 0);
      }
      oacc_l = MFMA16x16x32(ones, pf, oacc_l, 0, 0, 0);
      __builtin_amdgcn_s_setprio(0);
    }
    asm volatile("" ::: "memory");
    __builtin_amdgcn_s_barrier();
  }
#undef STAGE
  float linv = 1.f / oacc_l[0];
  const int b = bh >> 4, h = bh & 15;
  size_t rowoff = ((size_t)b * 2048 + qrow0 + qq) * 2048 + h * 128 + 4 * g;
#pragma unroll
  for (int d = 0; d < 8; ++d) {
    u32 lo = cvtpk(oacc[d][0] * linv, oacc[d][1] * linv);
    u32 hi = cvtpk(oacc[d][2] * linv, oacc[d][3] * linv);
    u64 w = (u64)lo | ((u64)hi << 32);
    *(u64*)&O[rowoff + d * 16] = w;
  }
}

// ---------------------------------------------------------------------------
extern "C" void kernel_launch(void* const* d_in, const int* in_sizes, int n_in,
                              void* d_out, int out_size, void* d_ws,
                              size_t ws_size, hipStream_t stream) {
  (void)in_sizes; (void)n_in; (void)out_size;
  const float* x = (const float*)d_in[0];
  const float* fc = (const float*)d_in[1];
  const float* wqa = (const float*)d_in[2];
  const float* wqb = (const float*)d_in[3];
  const float* qnw = (const float*)d_in[4];
  const float* wkva = (const float*)d_in[5];
  const float* kvnw = (const float*)d_in[6];
  const float* wkvb = (const float*)d_in[7];
  const float* wo = (const float*)d_in[8];
  float* out = (float*)d_out;
  char* ws = (char*)d_ws;

  size_t off = 0;
  auto alloc = [&](size_t bytes) {
    size_t o = off;
    off += (bytes + 255) & ~(size_t)255;
    return o;
  };
  const size_t o_xbf = alloc(16777216);   // x bf16; later aliased by attn_out
  const size_t o_wa = alloc(5242880);     // merged [wq_a;wkv_a;pad] bf16 1280x2048
  const size_t o_wqb = alloc(3145728);
  const size_t o_wkvb = alloc(4194304);
  const size_t o_wo = alloc(8388608);
  const size_t o_qln = alloc(4194304);
  const size_t o_kvln = alloc(4194304);
  const size_t o_ap = alloc(10485760);    // aproj bf16 4096x1280
  const size_t o_qbf = alloc(25165824);   // q packed [bh][s][192] (pre-scaled)
  const size_t o_kbf = alloc(25165824);   // k packed [bh][s][192]
  const size_t o_vt = alloc(16777216);    // v^T [bh][128][2048]
  if (ws_size < off) return;

  u16* xbf = (u16*)(ws + o_xbf);
  u16* wab = (u16*)(ws + o_wa);
  u16* wqbb = (u16*)(ws + o_wqb);
  u16* wkvbb = (u16*)(ws + o_wkvb);
  u16* wob = (u16*)(ws + o_wo);
  u16* qlatn = (u16*)(ws + o_qln);
  u16* kvlatn = (u16*)(ws + o_kvln);
  u16* ap = (u16*)(ws + o_ap);
  u16* qbf = (u16*)(ws + o_qbf);
  u16* kbf = (u16*)(ws + o_kbf);
  u16* vt = (u16*)(ws + o_vt);
  u16* attnbf = (u16*)(ws + o_xbf);

  cvt_all<<<2048, 256, 0, stream>>>(x, wqa, wkva, wqb, wkvb, wo,
                                    xbf, wab, wab + 1048576, wqbb, wkvbb, wob);

  // merged down-projection (N padded 1088->1280), bf16 out; 320 blocks
  gemm8<128, 128, 1><<<dim3(10, 32), 512, 0, stream>>>(
      xbf, wab, ap, 4096, 1280, 2048, nullptr, nullptr);
  rmsnorm2<<<8192, 256, 0, stream>>>(ap, qnw, kvnw, qlatn, kvlatn);
  rope_kpe_bcast<<<512, 256, 0, stream>>>(ap, fc, kbf);

  // q GEMM + fused rope/scale/pack -> qbf; 384 blocks
  gemm8<128, 256, 2><<<dim3(12, 32), 512, 0, stream>>>(
      qlatn, wqbb, qbf, 4096, 3072, 512, fc, nullptr);

  // kv GEMM + fused pack-k / transpose-v -> kbf, vt; 512 blocks
  gemm8<128, 256, 3><<<dim3(16, 32), 512, 0, stream>>>(
      kvlatn, wkvbb, kbf, 4096, 4096, 512, nullptr, vt);

  // attention (1024 blocks x 256 thr) + output projection
  flash_attn<<<1024, 256, 0, stream>>>(qbf, kbf, vt, attnbf);
  gemm8<128, 128, 0><<<dim3(16, 32), 512, 0, stream>>>(
      attnbf, wob, out, 4096, 2048, 2048, nullptr, nullptr);
}